// Round 4
// baseline (6191.799 us; speedup 1.0000x reference)
//
#include <hip/hip_runtime.h>
#include <hip/hip_fp16.h>
#include <string.h>

// Problem constants (match reference)
constexpr int B = 64, T = 512, I = 512, H = 512, G = 2048; // G = 4*H

typedef _Float16 half8 __attribute__((ext_vector_type(8)));
typedef float floatx4 __attribute__((ext_vector_type(4)));

// ---------------------------------------------------------------------------
// Phase 1: xg[t][g][b] = sum_i x[b][t][i] * W_ih[g][i] + (b_ih[g] + b_hh[g])
// stored as f16. (unchanged, proven)
// ---------------------------------------------------------------------------
__global__ __launch_bounds__(256, 2) void xg_gemm(
    const float* __restrict__ x,     // [B][T][I]
    const float* __restrict__ W_ih,  // [G][I]
    const float* __restrict__ b_ih,
    const float* __restrict__ b_hh,
    _Float16* __restrict__ xg)       // [T][G][B]
{
    const int tid  = threadIdx.x;
    const int wave = tid >> 6, lane = tid & 63;
    const int quad = lane >> 4, col = lane & 15;
    const int rowA = blockIdx.x * 128 + wave * 16;
    const int rowB = rowA + 64;

    __shared__ __align__(16) _Float16 xs[64][264];

    half8 wfA[16], wfB[16];
    {
        const float* wpA = W_ih + (size_t)(rowA + col) * I;
        const float* wpB = W_ih + (size_t)(rowB + col) * I;
#pragma unroll
        for (int kc = 0; kc < 16; ++kc) {
            half8 vA, vB;
#pragma unroll
            for (int j = 0; j < 8; ++j) {
                vA[j] = (_Float16)wpA[kc * 32 + quad * 8 + j];
                vB[j] = (_Float16)wpB[kc * 32 + quad * 8 + j];
            }
            wfA[kc] = vA; wfB[kc] = vB;
        }
    }
    float biasA[4], biasB[4];
#pragma unroll
    for (int r = 0; r < 4; ++r) {
        biasA[r] = b_ih[rowA + quad * 4 + r] + b_hh[rowA + quad * 4 + r];
        biasB[r] = b_ih[rowB + quad * 4 + r] + b_hh[rowB + quad * 4 + r];
    }

    for (int ti = 0; ti < 4; ++ti) {
        const int t = blockIdx.y * 4 + ti;
        floatx4 accA[4], accB[4];
#pragma unroll
        for (int nt = 0; nt < 4; ++nt) {
            accA[nt] = (floatx4){0.f, 0.f, 0.f, 0.f};
            accB[nt] = (floatx4){0.f, 0.f, 0.f, 0.f};
        }

        for (int hfl = 0; hfl < 2; ++hfl) {
            __syncthreads();
#pragma unroll 4
            for (int c = 0; c < 16; ++c) {
                int idx = c * 256 + tid;
                int row = idx >> 6;
                int kk  = (idx & 63) * 4;
                const float4 v = *(const float4*)(x + ((size_t)row * T + t) * I + hfl * 256 + kk);
                xs[row][kk + 0] = (_Float16)v.x;
                xs[row][kk + 1] = (_Float16)v.y;
                xs[row][kk + 2] = (_Float16)v.z;
                xs[row][kk + 3] = (_Float16)v.w;
            }
            __syncthreads();
#pragma unroll
            for (int kc = 0; kc < 8; ++kc) {
#pragma unroll
                for (int nt = 0; nt < 4; ++nt) {
                    const half8 bfr = *(const half8*)&xs[nt * 16 + col][kc * 32 + quad * 8];
                    accA[nt] = __builtin_amdgcn_mfma_f32_16x16x32_f16(
                        wfA[hfl * 8 + kc], bfr, accA[nt], 0, 0, 0);
                    accB[nt] = __builtin_amdgcn_mfma_f32_16x16x32_f16(
                        wfB[hfl * 8 + kc], bfr, accB[nt], 0, 0, 0);
                }
            }
        }
#pragma unroll
        for (int nt = 0; nt < 4; ++nt) {
            int b = nt * 16 + col;
#pragma unroll
            for (int r = 0; r < 4; ++r) {
                xg[((size_t)t * G + rowA + quad * 4 + r) * B + b] = (_Float16)(accA[nt][r] + biasA[r]);
                xg[((size_t)t * G + rowB + quad * 4 + r) * B + b] = (_Float16)(accB[nt][r] + biasB[r]);
            }
        }
    }
}

// ---------------------------------------------------------------------------
// Phase 2: persistent recurrence with SELF-VALIDATING h records.
//
// R4 theory: R0/R1/R3 all sit at ~5.5-6us/step regardless of barrier
// mechanics => the floor is serial hop count x LLC hop latency (~2-3k cy/hop,
// 4 hops: store-ack, flag propagate, poll detect, payload load). Collapse to
// ~1.5 hops: each 8B record = {2 x f16 h, u32 epoch tag}, stored with ONE
// __hip_atomic_store(u64) (8B aligned = single-copy atomic, the same
// primitive proven in R0-R3; avoids R2's 16B tearing). Producer is
// fire-and-forget (no drain, no flag, no syncthreads). Consumer polls the
// records THEMSELVES: load u64, check tag, payload is in the same register.
// Detection IS the data. Records double-buffered by parity; step t reads
// buf[t&1] expecting tag t+1, publishes tag t+2 to buf[(t+1)&1].
//
// Freeze induction (no barriers): X overwrites its tag-(t+1) records (with
// t+3) only after consuming ALL tag-(t+2) records; Z publishes its t+2
// record only after consuming all t+1 records. So any reader of tag-(t+1)
// records finishes before they are overwritten. Tag mismatch => retry
// (monotonic); 8B atomicity excludes torn reads.
//
// Loads staggered 8 kc ahead so spins are latency-covered; MFMA consumes
// per-kc; xg prefetch issues AFTER record preloads so HBM latency stays off
// the record s_waitcnt path.
// ---------------------------------------------------------------------------
__global__ __launch_bounds__(256, 1) void lstm_rec(
    const float* __restrict__ h0,    // [B][H]
    const float* __restrict__ c0,    // [B][H]
    const float* __restrict__ W_hh,  // [G][H]
    const _Float16* __restrict__ xg, // [T][G][B]
    unsigned long long* __restrict__ rec, // [2][4][16][256] u64, zeroed
    float* __restrict__ out)         // [B][T][H] ++ hT[B][H] ++ cT[B][H]
{
    const int blk  = blockIdx.x;
    const int bg   = blk & 3;        // batch group (16 batches)
    const int hg   = blk >> 2;       // H slice (32 h-indices)
    const int tid  = threadIdx.x;
    const int wave = tid >> 6, lane = tid & 63;
    const int quad = lane >> 4, col = lane & 15;

    const int bglob = bg * 16 + col;       // this lane's batch
    const int hbase = hg * 32 + wave * 8;  // this wave's 8 h-indices

    // A-fragment rows (m = col): tile0 = [i(8), f(8)], tile1 = [g(8), o(8)]
    int arow0 = (col < 8) ? (hbase + col) : (512 + hbase + col - 8);
    int arow1 = arow0 + 1024;
    half8 wf0[16], wf1[16];
#pragma unroll
    for (int kc = 0; kc < 16; ++kc) {
        const float* p0 = W_hh + (size_t)arow0 * H + kc * 32 + quad * 8;
        const float* p1 = W_hh + (size_t)arow1 * H + kc * 32 + quad * 8;
        half8 v0, v1;
#pragma unroll
        for (int j = 0; j < 8; ++j) { v0[j] = (_Float16)p0[j]; v1[j] = (_Float16)p1[j]; }
        wf0[kc] = v0; wf1[kc] = v1;
    }

    // C rows this lane holds (lr = quad*4+r): xg row indices
    int xrow0[4], xrow1[4];
#pragma unroll
    for (int r = 0; r < 4; ++r) {
        int lr = quad * 4 + r;
        xrow0[r] = (lr < 8) ? (hbase + lr) : (512 + hbase + lr - 8);
        xrow1[r] = xrow0[r] + 1024;
    }

    // After xor-32 exchange this lane updates h-index hbase + (quad&1)*4 + r
    float c[4];
#pragma unroll
    for (int r = 0; r < 4; ++r)
        c[r] = c0[(size_t)bglob * H + hbase + (quad & 1) * 4 + r];

    // record buffers (u64 units); group block = 16 batches x 256 pairs
    unsigned long long* rb0 = rec + (size_t)(0 * 4 + bg) * 16 * 256;
    unsigned long long* rb1 = rec + (size_t)(1 * 4 + bg) * 16 * 256;

    // producer: this lane (quad<2) owns h-pair records myp, myp+1 of batch col
    const int myp   = (hbase + (quad & 1) * 4) >> 1;      // even pair index
    const int mybase = col * 256 + myp;

    // consumer: records cbase + kc*16 + {0..3} give h[col][kc*32+quad*8+0..7]
    const int cbase = col * 256 + quad * 4;

    // init: publish h0 with tag 1 (fire-and-forget)
    if (quad < 2) {
        _Float16 a01[2] = {(_Float16)h0[(size_t)bglob * H + hbase + (quad & 1) * 4 + 0],
                           (_Float16)h0[(size_t)bglob * H + hbase + (quad & 1) * 4 + 1]};
        _Float16 a23[2] = {(_Float16)h0[(size_t)bglob * H + hbase + (quad & 1) * 4 + 2],
                           (_Float16)h0[(size_t)bglob * H + hbase + (quad & 1) * 4 + 3]};
        unsigned lo0, lo1;
        __builtin_memcpy(&lo0, a01, 4);
        __builtin_memcpy(&lo1, a23, 4);
        unsigned long long r0 = (unsigned long long)lo0 | (1ull << 32);
        unsigned long long r1 = (unsigned long long)lo1 | (1ull << 32);
        __hip_atomic_store(rb0 + mybase,     r0, __ATOMIC_RELAXED, __HIP_MEMORY_SCOPE_AGENT);
        __hip_atomic_store(rb0 + mybase + 1, r1, __ATOMIC_RELAXED, __HIP_MEMORY_SCOPE_AGENT);
    }

    // prefetch xg for t=0 (plain cached loads; xg constant during phase 2)
    float xp0[4], xp1[4];
#pragma unroll
    for (int r = 0; r < 4; ++r) {
        xp0[r] = (float)xg[(size_t)xrow0[r] * B + bglob];
        xp1[r] = (float)xg[(size_t)xrow1[r] * B + bglob];
    }

    float hh[4] = {0.f, 0.f, 0.f, 0.f};

    for (int t = 0; t < T; ++t) {
        unsigned long long* rcur = (t & 1) ? rb1 : rb0;
        unsigned long long* rnxt = (t & 1) ? rb0 : rb1;
        const unsigned tg = (unsigned)(t + 1);

        // staggered record window: preload kc = 0..7 (32 x 8B, pipelined)
        unsigned long long v[16][4];
#pragma unroll
        for (int kc = 0; kc < 8; ++kc)
#pragma unroll
            for (int i = 0; i < 4; ++i)
                v[kc][i] = __hip_atomic_load(rcur + cbase + kc * 16 + i,
                                             __ATOMIC_RELAXED, __HIP_MEMORY_SCOPE_AGENT);

        // xg prefetch for t+1 AFTER record preloads (keeps HBM latency off
        // the record waitcnt path; result needed only at next step's gates)
        float xn0[4] = {0, 0, 0, 0}, xn1[4] = {0, 0, 0, 0};
        if (t + 1 < T) {
            const _Float16* xgt = xg + (size_t)(t + 1) * G * B;
#pragma unroll
            for (int r = 0; r < 4; ++r) {
                xn0[r] = (float)xgt[(size_t)xrow0[r] * B + bglob];
                xn1[r] = (float)xgt[(size_t)xrow1[r] * B + bglob];
            }
        }

        floatx4 a0a = (floatx4){0.f, 0.f, 0.f, 0.f}, a0b = a0a;
        floatx4 a1a = a0a, a1b = a0a;

#pragma unroll
        for (int kc = 0; kc < 16; ++kc) {
            // keep the window 8 deep: issue kc+8's loads now
            if (kc < 8) {
#pragma unroll
                for (int i = 0; i < 4; ++i)
                    v[kc + 8][i] = __hip_atomic_load(rcur + cbase + (kc + 8) * 16 + i,
                                                     __ATOMIC_RELAXED, __HIP_MEMORY_SCOPE_AGENT);
            }
            // spin until this kc's 4 records carry tag t+1 (wave-coherent)
            for (;;) {
                unsigned bad = ((unsigned)(v[kc][0] >> 32) ^ tg)
                             | ((unsigned)(v[kc][1] >> 32) ^ tg)
                             | ((unsigned)(v[kc][2] >> 32) ^ tg)
                             | ((unsigned)(v[kc][3] >> 32) ^ tg);
                if (__all(bad == 0u)) break;
#pragma unroll
                for (int i = 0; i < 4; ++i)
                    v[kc][i] = __hip_atomic_load(rcur + cbase + kc * 16 + i,
                                                 __ATOMIC_RELAXED, __HIP_MEMORY_SCOPE_AGENT);
            }
            // payload IS the detection value: pack 4 low-dwords -> 8 f16
            unsigned ww[4] = {(unsigned)v[kc][0], (unsigned)v[kc][1],
                              (unsigned)v[kc][2], (unsigned)v[kc][3]};
            half8 bfr;
            __builtin_memcpy(&bfr, ww, 16);
            if (kc & 1) {
                a0b = __builtin_amdgcn_mfma_f32_16x16x32_f16(wf0[kc], bfr, a0b, 0, 0, 0);
                a1b = __builtin_amdgcn_mfma_f32_16x16x32_f16(wf1[kc], bfr, a1b, 0, 0, 0);
            } else {
                a0a = __builtin_amdgcn_mfma_f32_16x16x32_f16(wf0[kc], bfr, a0a, 0, 0, 0);
                a1a = __builtin_amdgcn_mfma_f32_16x16x32_f16(wf1[kc], bfr, a1a, 0, 0, 0);
            }
        }

        // add prefetched xg, exchange i/f and g/o halves across lane^32
        float p0[4], p1[4];
#pragma unroll
        for (int r = 0; r < 4; ++r) {
            p0[r] = a0a[r] + a0b[r] + xp0[r];
            p1[r] = a1a[r] + a1b[r] + xp1[r];
        }
        float e0[4], e1[4];
#pragma unroll
        for (int r = 0; r < 4; ++r) {
            e0[r] = __shfl_xor(p0[r], 32);
            e1[r] = __shfl_xor(p1[r], 32);
        }
#pragma unroll
        for (int r = 0; r < 4; ++r) {
            float iv = (quad < 2) ? p0[r] : e0[r];
            float fv = (quad < 2) ? e0[r] : p0[r];
            float gv = (quad < 2) ? p1[r] : e1[r];
            float ov = (quad < 2) ? e1[r] : p1[r];
            float ii = 1.f / (1.f + __expf(-iv));
            float ff = 1.f / (1.f + __expf(-fv));
            float eg = __expf(-2.f * gv);
            float gg = (1.f - eg) / (1.f + eg);
            float oo = 1.f / (1.f + __expf(-ov));
            float cn = ff * c[r] + ii * gg;
            c[r] = cn;
            float ec = __expf(-2.f * cn);
            hh[r] = oo * ((1.f - ec) / (1.f + ec));
        }

        // publish h_{t+1} with embedded tag t+2: two 8B atomic stores,
        // fire-and-forget (no drain, no flag, no syncthreads)
        if (quad < 2) {
            _Float16 a01[2] = {(_Float16)hh[0], (_Float16)hh[1]};
            _Float16 a23[2] = {(_Float16)hh[2], (_Float16)hh[3]};
            unsigned lo0, lo1;
            __builtin_memcpy(&lo0, a01, 4);
            __builtin_memcpy(&lo1, a23, 4);
            unsigned long long r0 = (unsigned long long)lo0 | ((unsigned long long)(t + 2) << 32);
            unsigned long long r1 = (unsigned long long)lo1 | ((unsigned long long)(t + 2) << 32);
            __hip_atomic_store(rnxt + mybase,     r0, __ATOMIC_RELAXED, __HIP_MEMORY_SCOPE_AGENT);
            __hip_atomic_store(rnxt + mybase + 1, r1, __ATOMIC_RELAXED, __HIP_MEMORY_SCOPE_AGENT);
            // out store: plain cached, off the exchange path entirely
            *(float4*)(out + ((size_t)bglob * T + t) * H + hbase + (quad & 1) * 4) =
                make_float4(hh[0], hh[1], hh[2], hh[3]);
        }

#pragma unroll
        for (int r = 0; r < 4; ++r) { xp0[r] = xn0[r]; xp1[r] = xn1[r]; }
    }

    // final h_T, c_T
    if (quad < 2) {
        float* hT = out + (size_t)B * T * H;
        float* cT = hT + (size_t)B * H;
#pragma unroll
        for (int r = 0; r < 4; ++r) {
            int jj = (quad & 1) * 4 + r;
            hT[(size_t)bglob * H + hbase + jj] = hh[r];
            cT[(size_t)bglob * H + hbase + jj] = c[r];
        }
    }
}

// ---------------------------------------------------------------------------
extern "C" void kernel_launch(void* const* d_in, const int* in_sizes, int n_in,
                              void* d_out, int out_size, void* d_ws, size_t ws_size,
                              hipStream_t stream) {
    const float* x    = (const float*)d_in[0];
    const float* h0   = (const float*)d_in[1];
    const float* c0   = (const float*)d_in[2];
    const float* W_ih = (const float*)d_in[3];
    const float* W_hh = (const float*)d_in[4];
    const float* b_ih = (const float*)d_in[5];
    const float* b_hh = (const float*)d_in[6];
    float* out = (float*)d_out;

    // workspace layout:
    //   [0, 256KiB)        : tagged h records [2][4][16][256] u64, zeroed
    //   [256KiB, +T*G*B*2) : xg (f16), 128 MiB
    constexpr size_t REC_BYTES = (size_t)2 * 4 * 16 * 256 * 8; // 262144
    unsigned long long* rec = (unsigned long long*)d_ws;
    _Float16* xg = (_Float16*)((char*)d_ws + REC_BYTES);

    hipMemsetAsync(d_ws, 0, REC_BYTES, stream);

    xg_gemm<<<dim3(16, 128), 256, 0, stream>>>(x, W_ih, b_ih, b_hh, xg);
    lstm_rec<<<64, 256, 0, stream>>>(h0, c0, W_hh, xg, rec, out);
}

// Round 5
// 3309.851 us; speedup vs baseline: 1.8707x; 1.8707x over previous
//
#include <hip/hip_runtime.h>
#include <hip/hip_fp16.h>
#include <string.h>

// Problem constants (match reference)
constexpr int B = 64, T = 512, I = 512, H = 512, G = 2048; // G = 4*H

typedef _Float16 half8 __attribute__((ext_vector_type(8)));
typedef float floatx4 __attribute__((ext_vector_type(4)));

// ---------------------------------------------------------------------------
// Phase 1: xg[t][g][b] = sum_i x[b][t][i] * W_ih[g][i] + (b_ih[g] + b_hh[g])
// stored as f16. (unchanged, proven)
// ---------------------------------------------------------------------------
__global__ __launch_bounds__(256, 2) void xg_gemm(
    const float* __restrict__ x,     // [B][T][I]
    const float* __restrict__ W_ih,  // [G][I]
    const float* __restrict__ b_ih,
    const float* __restrict__ b_hh,
    _Float16* __restrict__ xg)       // [T][G][B]
{
    const int tid  = threadIdx.x;
    const int wave = tid >> 6, lane = tid & 63;
    const int quad = lane >> 4, col = lane & 15;
    const int rowA = blockIdx.x * 128 + wave * 16;
    const int rowB = rowA + 64;

    __shared__ __align__(16) _Float16 xs[64][264];

    half8 wfA[16], wfB[16];
    {
        const float* wpA = W_ih + (size_t)(rowA + col) * I;
        const float* wpB = W_ih + (size_t)(rowB + col) * I;
#pragma unroll
        for (int kc = 0; kc < 16; ++kc) {
            half8 vA, vB;
#pragma unroll
            for (int j = 0; j < 8; ++j) {
                vA[j] = (_Float16)wpA[kc * 32 + quad * 8 + j];
                vB[j] = (_Float16)wpB[kc * 32 + quad * 8 + j];
            }
            wfA[kc] = vA; wfB[kc] = vB;
        }
    }
    float biasA[4], biasB[4];
#pragma unroll
    for (int r = 0; r < 4; ++r) {
        biasA[r] = b_ih[rowA + quad * 4 + r] + b_hh[rowA + quad * 4 + r];
        biasB[r] = b_ih[rowB + quad * 4 + r] + b_hh[rowB + quad * 4 + r];
    }

    for (int ti = 0; ti < 4; ++ti) {
        const int t = blockIdx.y * 4 + ti;
        floatx4 accA[4], accB[4];
#pragma unroll
        for (int nt = 0; nt < 4; ++nt) {
            accA[nt] = (floatx4){0.f, 0.f, 0.f, 0.f};
            accB[nt] = (floatx4){0.f, 0.f, 0.f, 0.f};
        }

        for (int hfl = 0; hfl < 2; ++hfl) {
            __syncthreads();
#pragma unroll 4
            for (int c = 0; c < 16; ++c) {
                int idx = c * 256 + tid;
                int row = idx >> 6;
                int kk  = (idx & 63) * 4;
                const float4 v = *(const float4*)(x + ((size_t)row * T + t) * I + hfl * 256 + kk);
                xs[row][kk + 0] = (_Float16)v.x;
                xs[row][kk + 1] = (_Float16)v.y;
                xs[row][kk + 2] = (_Float16)v.z;
                xs[row][kk + 3] = (_Float16)v.w;
            }
            __syncthreads();
#pragma unroll
            for (int kc = 0; kc < 8; ++kc) {
#pragma unroll
                for (int nt = 0; nt < 4; ++nt) {
                    const half8 bfr = *(const half8*)&xs[nt * 16 + col][kc * 32 + quad * 8];
                    accA[nt] = __builtin_amdgcn_mfma_f32_16x16x32_f16(
                        wfA[hfl * 8 + kc], bfr, accA[nt], 0, 0, 0);
                    accB[nt] = __builtin_amdgcn_mfma_f32_16x16x32_f16(
                        wfB[hfl * 8 + kc], bfr, accB[nt], 0, 0, 0);
                }
            }
        }
#pragma unroll
        for (int nt = 0; nt < 4; ++nt) {
            int b = nt * 16 + col;
#pragma unroll
            for (int r = 0; r < 4; ++r) {
                xg[((size_t)t * G + rowA + quad * 4 + r) * B + b] = (_Float16)(accA[nt][r] + biasA[r]);
                xg[((size_t)t * G + rowB + quad * 4 + r) * B + b] = (_Float16)(accB[nt][r] + biasB[r]);
            }
        }
    }
}

// ---------------------------------------------------------------------------
// Phase 2: batch-partitioned persistent recurrence (R3 skeleton).
//
// R5 change -- vmcnt decoupling. ISA fact: vmcnt is one in-order counter, so
// the spin's per-poll s_waitcnt vmcnt(0) waits for ALL outstanding VMEM. In
// R0/R3 the 8 xg prefetch loads (HBM, ~1.2us) were issued between signal and
// spin and left outstanding => the FIRST poll of every step stalled on the
// full xg HBM latency, serializing it into the sync window. (R4's per-kc
// retries amplified the same coupling -> 2x regression; its 375ns/retry also
// calibrates the LLC round trip at ~900cy.)
// Fix: after the signal, issue xg(t+1) loads AND force them to retire
// (convert + asm pin) BEFORE entering the spin. The xg drain then overlaps
// producer flag propagation instead of stacking onto every poll. Out-store
// moved before the single vmcnt(0) drain so no store-ack is outstanding
// during the spin either. Flags/spin/h-path identical to R3.
// ---------------------------------------------------------------------------
__global__ __launch_bounds__(256, 1) void lstm_rec(
    const float* __restrict__ h0,    // [B][H]
    const float* __restrict__ c0,    // [B][H]
    const float* __restrict__ W_hh,  // [G][H]
    const _Float16* __restrict__ xg, // [T][G][B]
    _Float16* __restrict__ hbuf,     // [2][4][16][512] f16
    unsigned int* __restrict__ flags,// [4][16] block epochs, 64B apart, zeroed
    float* __restrict__ out)         // [B][T][H] ++ hT[B][H] ++ cT[B][H]
{
    const int blk  = blockIdx.x;
    const int bg   = blk & 3;        // batch group (16 batches)
    const int hg   = blk >> 2;       // H slice (32 h-indices)
    const int tid  = threadIdx.x;
    const int wave = tid >> 6, lane = tid & 63;
    const int quad = lane >> 4, col = lane & 15;

    const int bglob = bg * 16 + col;       // this lane's batch
    const int hbase = hg * 32 + wave * 8;  // this wave's 8 h-indices

    unsigned int* flg   = flags + bg * 256;   // group's 16 flags (64B stride)
    unsigned int* myflg = flg + hg * 16;      // this block's flag dword

    // A-fragment rows (m = col): tile0 = [i(8), f(8)], tile1 = [g(8), o(8)]
    int arow0 = (col < 8) ? (hbase + col) : (512 + hbase + col - 8);
    int arow1 = arow0 + 1024;
    half8 wf0[16], wf1[16];
#pragma unroll
    for (int kc = 0; kc < 16; ++kc) {
        const float* p0 = W_hh + (size_t)arow0 * H + kc * 32 + quad * 8;
        const float* p1 = W_hh + (size_t)arow1 * H + kc * 32 + quad * 8;
        half8 v0, v1;
#pragma unroll
        for (int j = 0; j < 8; ++j) { v0[j] = (_Float16)p0[j]; v1[j] = (_Float16)p1[j]; }
        wf0[kc] = v0; wf1[kc] = v1;
    }

    // C rows this lane holds (lr = quad*4+r): xg row indices
    int xrow0[4], xrow1[4];
#pragma unroll
    for (int r = 0; r < 4; ++r) {
        int lr = quad * 4 + r;
        xrow0[r] = (lr < 8) ? (hbase + lr) : (512 + hbase + lr - 8);
        xrow1[r] = xrow0[r] + 1024;
    }

    // After xor-32 exchange this lane updates h-index hbase + (quad&1)*4 + r
    float c[4];
#pragma unroll
    for (int r = 0; r < 4; ++r)
        c[r] = c0[(size_t)bglob * H + hbase + (quad & 1) * 4 + r];

    // group h double buffer: hbuf[buf][bg][16][512]
    _Float16* hb0 = hbuf + ((size_t)0 * 4 + bg) * 16 * 512;
    _Float16* hb1 = hbuf + ((size_t)1 * 4 + bg) * 16 * 512;

    // init buffer 0 with h0 (each (bg,h) written once by its owner wave)
    if (quad < 2) {
        _Float16 v4[4];
#pragma unroll
        for (int r = 0; r < 4; ++r)
            v4[r] = (_Float16)h0[(size_t)bglob * H + hbase + (quad & 1) * 4 + r];
        unsigned long long uv; __builtin_memcpy(&uv, v4, 8);
        __hip_atomic_store((unsigned long long*)(hb0 + (size_t)col * 512 + hbase + (quad & 1) * 4),
                           uv, __ATOMIC_RELAXED, __HIP_MEMORY_SCOPE_AGENT);
    }
    asm volatile("s_waitcnt vmcnt(0)" ::: "memory");
    __syncthreads();
    if (tid == 0)
        __hip_atomic_store(myflg, 1u, __ATOMIC_RELAXED, __HIP_MEMORY_SCOPE_AGENT);

    // prefetch xg(t=0) and RETIRE it before the epoch-1 spin (vmcnt decouple)
    float xp0[4], xp1[4];
#pragma unroll
    for (int r = 0; r < 4; ++r) {
        xp0[r] = (float)xg[(size_t)xrow0[r] * B + bglob];
        xp1[r] = (float)xg[(size_t)xrow1[r] * B + bglob];
    }
    asm volatile("" : "+v"(xp0[0]), "+v"(xp0[1]), "+v"(xp0[2]), "+v"(xp0[3]),
                      "+v"(xp1[0]), "+v"(xp1[1]), "+v"(xp1[2]), "+v"(xp1[3]) :: "memory");

    // wait for all 16 block flags of this group to reach epoch 1
    for (;;) {
        unsigned f = __hip_atomic_load(flg + (lane & 15) * 16,
                                       __ATOMIC_RELAXED, __HIP_MEMORY_SCOPE_AGENT);
        if (__all(f >= 1u)) break;
    }
    asm volatile("" ::: "memory");

    float hh[4] = {0.f, 0.f, 0.f, 0.f};

    for (int t = 0; t < T; ++t) {
        const _Float16* hcur = (t & 1) ? hb1 : hb0;
        _Float16*       hnxt = (t & 1) ? hb0 : hb1;

        // issue all coherent h loads first so they pipeline (one latency)
        unsigned long long hu0[16], hu1[16];
#pragma unroll
        for (int kc = 0; kc < 16; ++kc) {
            unsigned long long* hp =
                (unsigned long long*)(hcur + (size_t)col * 512 + kc * 32 + quad * 8);
            hu0[kc] = __hip_atomic_load(hp,     __ATOMIC_RELAXED, __HIP_MEMORY_SCOPE_AGENT);
            hu1[kc] = __hip_atomic_load(hp + 1, __ATOMIC_RELAXED, __HIP_MEMORY_SCOPE_AGENT);
        }

        // ---- MFMA: 4 independent 8-deep chains for latency hiding
        floatx4 acc0a = (floatx4){0.f,0.f,0.f,0.f}, acc0b = acc0a;
        floatx4 acc1a = acc0a, acc1b = acc0a;
#pragma unroll
        for (int kc = 0; kc < 8; ++kc) {
            half8 bfrA, bfrB;
            __builtin_memcpy(&bfrA, &hu0[kc], 8);
            __builtin_memcpy((char*)&bfrA + 8, &hu1[kc], 8);
            __builtin_memcpy(&bfrB, &hu0[kc + 8], 8);
            __builtin_memcpy((char*)&bfrB + 8, &hu1[kc + 8], 8);
            acc0a = __builtin_amdgcn_mfma_f32_16x16x32_f16(wf0[kc],     bfrA, acc0a, 0, 0, 0);
            acc0b = __builtin_amdgcn_mfma_f32_16x16x32_f16(wf0[kc + 8], bfrB, acc0b, 0, 0, 0);
            acc1a = __builtin_amdgcn_mfma_f32_16x16x32_f16(wf1[kc],     bfrA, acc1a, 0, 0, 0);
            acc1b = __builtin_amdgcn_mfma_f32_16x16x32_f16(wf1[kc + 8], bfrB, acc1b, 0, 0, 0);
        }

        // add prefetched xg, exchange i/f and g/o halves across lane^32
        float p0[4], p1[4];
#pragma unroll
        for (int r = 0; r < 4; ++r) {
            p0[r] = acc0a[r] + acc0b[r] + xp0[r];
            p1[r] = acc1a[r] + acc1b[r] + xp1[r];
        }
        float e0[4], e1[4];
#pragma unroll
        for (int r = 0; r < 4; ++r) {
            e0[r] = __shfl_xor(p0[r], 32);
            e1[r] = __shfl_xor(p1[r], 32);
        }
#pragma unroll
        for (int r = 0; r < 4; ++r) {
            float iv = (quad < 2) ? p0[r] : e0[r];
            float fv = (quad < 2) ? e0[r] : p0[r];
            float gv = (quad < 2) ? p1[r] : e1[r];
            float ov = (quad < 2) ? e1[r] : p1[r];
            float ii = 1.f / (1.f + __expf(-iv));
            float ff = 1.f / (1.f + __expf(-fv));
            float eg = __expf(-2.f * gv);
            float gg = (1.f - eg) / (1.f + eg);
            float oo = 1.f / (1.f + __expf(-ov));
            float cn = ff * c[r] + ii * gg;
            c[r] = cn;
            float ec = __expf(-2.f * cn);
            hh[r] = oo * ((1.f - ec) / (1.f + ec));
        }

        // h store (sc1 -> LLC) + out store: both BEFORE the single drain so
        // nothing remains outstanding during the spin
        if (quad < 2) {
            _Float16 v4[4] = {(_Float16)hh[0], (_Float16)hh[1],
                              (_Float16)hh[2], (_Float16)hh[3]};
            unsigned long long uv; __builtin_memcpy(&uv, v4, 8);
            __hip_atomic_store((unsigned long long*)(hnxt + (size_t)col * 512 + hbase + (quad & 1) * 4),
                               uv, __ATOMIC_RELAXED, __HIP_MEMORY_SCOPE_AGENT);
            *(float4*)(out + ((size_t)bglob * T + t) * H + hbase + (quad & 1) * 4) =
                make_float4(hh[0], hh[1], hh[2], hh[3]);
        }

        // ---- drain h+out stores, block-level signal: ONE store, own line
        asm volatile("s_waitcnt vmcnt(0)" ::: "memory");
        __syncthreads();
        if (tid == 0)
            __hip_atomic_store(myflg, (unsigned)(t + 2), __ATOMIC_RELAXED, __HIP_MEMORY_SCOPE_AGENT);

        if (t + 1 < T) {
            // xg(t+1): issue AND retire now -- its ~1.2us HBM latency overlaps
            // flag propagation, and the spin below polls with ZERO other VMEM
            // outstanding (each poll = one flag load, ~900cy round trip)
            const _Float16* xgt = xg + (size_t)(t + 1) * G * B;
#pragma unroll
            for (int r = 0; r < 4; ++r) {
                xp0[r] = (float)xgt[(size_t)xrow0[r] * B + bglob];
                xp1[r] = (float)xgt[(size_t)xrow1[r] * B + bglob];
            }
            asm volatile("" : "+v"(xp0[0]), "+v"(xp0[1]), "+v"(xp0[2]), "+v"(xp0[3]),
                              "+v"(xp1[0]), "+v"(xp1[1]), "+v"(xp1[2]), "+v"(xp1[3]) :: "memory");

            // spin: 16 distributed flag lines, one coalesced read per poll
            const unsigned tgt = (unsigned)(t + 2);
            for (;;) {
                unsigned f = __hip_atomic_load(flg + (lane & 15) * 16,
                                               __ATOMIC_RELAXED, __HIP_MEMORY_SCOPE_AGENT);
                if (__all(f >= tgt)) break;
            }
            asm volatile("" ::: "memory");
        }
    }

    // final h_T, c_T
    if (quad < 2) {
        float* hT = out + (size_t)B * T * H;
        float* cT = hT + (size_t)B * H;
#pragma unroll
        for (int r = 0; r < 4; ++r) {
            int jj = (quad & 1) * 4 + r;
            hT[(size_t)bglob * H + hbase + jj] = hh[r];
            cT[(size_t)bglob * H + hbase + jj] = c[r];
        }
    }
}

// ---------------------------------------------------------------------------
extern "C" void kernel_launch(void* const* d_in, const int* in_sizes, int n_in,
                              void* d_out, int out_size, void* d_ws, size_t ws_size,
                              hipStream_t stream) {
    const float* x    = (const float*)d_in[0];
    const float* h0   = (const float*)d_in[1];
    const float* c0   = (const float*)d_in[2];
    const float* W_ih = (const float*)d_in[3];
    const float* W_hh = (const float*)d_in[4];
    const float* b_ih = (const float*)d_in[5];
    const float* b_hh = (const float*)d_in[6];
    float* out = (float*)d_out;

    // workspace layout:
    //   [0, 4096)            : 4 groups x 16 block flags, 64B apart, zeroed
    //   [4096, +128KiB)      : h double buffer (f16)
    //   [next, +T*G*B*2)     : xg (f16), 128 MiB
    unsigned int* flags = (unsigned int*)d_ws;
    _Float16* hbuf = (_Float16*)((char*)d_ws + 4096);
    _Float16* xg   = (_Float16*)((char*)d_ws + 4096 + (size_t)2 * 4 * 16 * 512 * 2);

    hipMemsetAsync(d_ws, 0, 4096, stream);

    xg_gemm<<<dim3(16, 128), 256, 0, stream>>>(x, W_ih, b_ih, b_hh, xg);
    lstm_rec<<<64, 256, 0, stream>>>(h0, c0, W_hh, xg, hbuf, flags, out);
}

// Round 6
// 3306.185 us; speedup vs baseline: 1.8728x; 1.0011x over previous
//
#include <hip/hip_runtime.h>
#include <hip/hip_fp16.h>
#include <string.h>

// Problem constants (match reference)
constexpr int B = 64, T = 512, I = 512, H = 512, G = 2048; // G = 4*H

typedef _Float16 half8 __attribute__((ext_vector_type(8)));
typedef float floatx4 __attribute__((ext_vector_type(4)));

// ---------------------------------------------------------------------------
// Phase 1: xg[t][g][b] = sum_i x[b][t][i] * W_ih[g][i] + (b_ih[g] + b_hh[g])
// stored as f16. (unchanged, proven)
// ---------------------------------------------------------------------------
__global__ __launch_bounds__(256, 2) void xg_gemm(
    const float* __restrict__ x,     // [B][T][I]
    const float* __restrict__ W_ih,  // [G][I]
    const float* __restrict__ b_ih,
    const float* __restrict__ b_hh,
    _Float16* __restrict__ xg)       // [T][G][B]
{
    const int tid  = threadIdx.x;
    const int wave = tid >> 6, lane = tid & 63;
    const int quad = lane >> 4, col = lane & 15;
    const int rowA = blockIdx.x * 128 + wave * 16;
    const int rowB = rowA + 64;

    __shared__ __align__(16) _Float16 xs[64][264];

    half8 wfA[16], wfB[16];
    {
        const float* wpA = W_ih + (size_t)(rowA + col) * I;
        const float* wpB = W_ih + (size_t)(rowB + col) * I;
#pragma unroll
        for (int kc = 0; kc < 16; ++kc) {
            half8 vA, vB;
#pragma unroll
            for (int j = 0; j < 8; ++j) {
                vA[j] = (_Float16)wpA[kc * 32 + quad * 8 + j];
                vB[j] = (_Float16)wpB[kc * 32 + quad * 8 + j];
            }
            wfA[kc] = vA; wfB[kc] = vB;
        }
    }
    float biasA[4], biasB[4];
#pragma unroll
    for (int r = 0; r < 4; ++r) {
        biasA[r] = b_ih[rowA + quad * 4 + r] + b_hh[rowA + quad * 4 + r];
        biasB[r] = b_ih[rowB + quad * 4 + r] + b_hh[rowB + quad * 4 + r];
    }

    for (int ti = 0; ti < 4; ++ti) {
        const int t = blockIdx.y * 4 + ti;
        floatx4 accA[4], accB[4];
#pragma unroll
        for (int nt = 0; nt < 4; ++nt) {
            accA[nt] = (floatx4){0.f, 0.f, 0.f, 0.f};
            accB[nt] = (floatx4){0.f, 0.f, 0.f, 0.f};
        }

        for (int hfl = 0; hfl < 2; ++hfl) {
            __syncthreads();
#pragma unroll 4
            for (int c = 0; c < 16; ++c) {
                int idx = c * 256 + tid;
                int row = idx >> 6;
                int kk  = (idx & 63) * 4;
                const float4 v = *(const float4*)(x + ((size_t)row * T + t) * I + hfl * 256 + kk);
                xs[row][kk + 0] = (_Float16)v.x;
                xs[row][kk + 1] = (_Float16)v.y;
                xs[row][kk + 2] = (_Float16)v.z;
                xs[row][kk + 3] = (_Float16)v.w;
            }
            __syncthreads();
#pragma unroll
            for (int kc = 0; kc < 8; ++kc) {
#pragma unroll
                for (int nt = 0; nt < 4; ++nt) {
                    const half8 bfr = *(const half8*)&xs[nt * 16 + col][kc * 32 + quad * 8];
                    accA[nt] = __builtin_amdgcn_mfma_f32_16x16x32_f16(
                        wfA[hfl * 8 + kc], bfr, accA[nt], 0, 0, 0);
                    accB[nt] = __builtin_amdgcn_mfma_f32_16x16x32_f16(
                        wfB[hfl * 8 + kc], bfr, accB[nt], 0, 0, 0);
                }
            }
        }
#pragma unroll
        for (int nt = 0; nt < 4; ++nt) {
            int b = nt * 16 + col;
#pragma unroll
            for (int r = 0; r < 4; ++r) {
                xg[((size_t)t * G + rowA + quad * 4 + r) * B + b] = (_Float16)(accA[nt][r] + biasA[r]);
                xg[((size_t)t * G + rowB + quad * 4 + r) * B + b] = (_Float16)(accB[nt][r] + biasB[r]);
            }
        }
    }
}

// ---------------------------------------------------------------------------
// Phase 2: batch-partitioned persistent recurrence (R5 path, byte-identical)
// + R6 EXPERIMENT: 192 burner blocks (blk 64..255) on the otherwise-idle CUs.
//
// Theory: five structurally different sync designs (R0/R1/R3/R4/R5) all sit
// at 5.5-6.0us/step while the serial chain is only ~3500 CYCLES. A ~x3.5
// uniform inflation is exactly what an idle-clock (~650MHz) DPM state
// produces: 64/256 CUs occupied, VALUBusy 3%, waves parked in s_waitcnt.
// Burners present full VALU activity to the governor (4 independent FMA
// chains/thread), poll a done-counter every ~1us, exit when all 64 real
// blocks have finished. No memory traffic otherwise => no contention with
// the real path. Single-variable experiment on top of R5.
// ---------------------------------------------------------------------------
__global__ __launch_bounds__(256, 1) void lstm_rec(
    const float* __restrict__ h0,    // [B][H]
    const float* __restrict__ c0,    // [B][H]
    const float* __restrict__ W_hh,  // [G][H]
    const _Float16* __restrict__ xg, // [T][G][B]
    _Float16* __restrict__ hbuf,     // [2][4][16][512] f16
    unsigned int* __restrict__ flags,// [4][16] block epochs, 64B apart, zeroed
    unsigned int* __restrict__ done, // single dword, zeroed (own line)
    float* __restrict__ out)         // [B][T][H] ++ hT[B][H] ++ cT[B][H]
{
    const int blk  = blockIdx.x;
    const int tid  = threadIdx.x;

    // ---------------- burner blocks: keep the DPM governor at high clock ----
    if (blk >= 64) {
        float a0 = 1.0f + tid, a1 = 2.0f + tid, a2 = 3.0f + tid, a3 = 4.0f + tid;
        float s0 = 0.f, s1 = 1.f, s2 = 2.f, s3 = 3.f;
        const float bb = 1.0000001f;
        for (;;) {
            for (int i = 0; i < 512; ++i) {
                s0 = __builtin_fmaf(s0, bb, a0);
                s1 = __builtin_fmaf(s1, bb, a1);
                s2 = __builtin_fmaf(s2, bb, a2);
                s3 = __builtin_fmaf(s3, bb, a3);
            }
            if (__hip_atomic_load(done, __ATOMIC_RELAXED, __HIP_MEMORY_SCOPE_AGENT) >= 64u)
                break;
        }
        // keep the FMA loop alive without ever writing memory (rule #17)
        asm volatile("" :: "v"(s0), "v"(s1), "v"(s2), "v"(s3));
        return;
    }

    const int bg   = blk & 3;        // batch group (16 batches)
    const int hg   = blk >> 2;       // H slice (32 h-indices)
    const int wave = tid >> 6, lane = tid & 63;
    const int quad = lane >> 4, col = lane & 15;

    const int bglob = bg * 16 + col;       // this lane's batch
    const int hbase = hg * 32 + wave * 8;  // this wave's 8 h-indices

    unsigned int* flg   = flags + bg * 256;   // group's 16 flags (64B stride)
    unsigned int* myflg = flg + hg * 16;      // this block's flag dword

    // A-fragment rows (m = col): tile0 = [i(8), f(8)], tile1 = [g(8), o(8)]
    int arow0 = (col < 8) ? (hbase + col) : (512 + hbase + col - 8);
    int arow1 = arow0 + 1024;
    half8 wf0[16], wf1[16];
#pragma unroll
    for (int kc = 0; kc < 16; ++kc) {
        const float* p0 = W_hh + (size_t)arow0 * H + kc * 32 + quad * 8;
        const float* p1 = W_hh + (size_t)arow1 * H + kc * 32 + quad * 8;
        half8 v0, v1;
#pragma unroll
        for (int j = 0; j < 8; ++j) { v0[j] = (_Float16)p0[j]; v1[j] = (_Float16)p1[j]; }
        wf0[kc] = v0; wf1[kc] = v1;
    }

    // C rows this lane holds (lr = quad*4+r): xg row indices
    int xrow0[4], xrow1[4];
#pragma unroll
    for (int r = 0; r < 4; ++r) {
        int lr = quad * 4 + r;
        xrow0[r] = (lr < 8) ? (hbase + lr) : (512 + hbase + lr - 8);
        xrow1[r] = xrow0[r] + 1024;
    }

    // After xor-32 exchange this lane updates h-index hbase + (quad&1)*4 + r
    float c[4];
#pragma unroll
    for (int r = 0; r < 4; ++r)
        c[r] = c0[(size_t)bglob * H + hbase + (quad & 1) * 4 + r];

    // group h double buffer: hbuf[buf][bg][16][512]
    _Float16* hb0 = hbuf + ((size_t)0 * 4 + bg) * 16 * 512;
    _Float16* hb1 = hbuf + ((size_t)1 * 4 + bg) * 16 * 512;

    // init buffer 0 with h0 (each (bg,h) written once by its owner wave)
    if (quad < 2) {
        _Float16 v4[4];
#pragma unroll
        for (int r = 0; r < 4; ++r)
            v4[r] = (_Float16)h0[(size_t)bglob * H + hbase + (quad & 1) * 4 + r];
        unsigned long long uv; __builtin_memcpy(&uv, v4, 8);
        __hip_atomic_store((unsigned long long*)(hb0 + (size_t)col * 512 + hbase + (quad & 1) * 4),
                           uv, __ATOMIC_RELAXED, __HIP_MEMORY_SCOPE_AGENT);
    }
    asm volatile("s_waitcnt vmcnt(0)" ::: "memory");
    __syncthreads();
    if (tid == 0)
        __hip_atomic_store(myflg, 1u, __ATOMIC_RELAXED, __HIP_MEMORY_SCOPE_AGENT);

    // prefetch xg(t=0) and RETIRE it before the epoch-1 spin (vmcnt decouple)
    float xp0[4], xp1[4];
#pragma unroll
    for (int r = 0; r < 4; ++r) {
        xp0[r] = (float)xg[(size_t)xrow0[r] * B + bglob];
        xp1[r] = (float)xg[(size_t)xrow1[r] * B + bglob];
    }
    asm volatile("" : "+v"(xp0[0]), "+v"(xp0[1]), "+v"(xp0[2]), "+v"(xp0[3]),
                      "+v"(xp1[0]), "+v"(xp1[1]), "+v"(xp1[2]), "+v"(xp1[3]) :: "memory");

    // wait for all 16 block flags of this group to reach epoch 1
    for (;;) {
        unsigned f = __hip_atomic_load(flg + (lane & 15) * 16,
                                       __ATOMIC_RELAXED, __HIP_MEMORY_SCOPE_AGENT);
        if (__all(f >= 1u)) break;
    }
    asm volatile("" ::: "memory");

    float hh[4] = {0.f, 0.f, 0.f, 0.f};

    for (int t = 0; t < T; ++t) {
        const _Float16* hcur = (t & 1) ? hb1 : hb0;
        _Float16*       hnxt = (t & 1) ? hb0 : hb1;

        // issue all coherent h loads first so they pipeline (one latency)
        unsigned long long hu0[16], hu1[16];
#pragma unroll
        for (int kc = 0; kc < 16; ++kc) {
            unsigned long long* hp =
                (unsigned long long*)(hcur + (size_t)col * 512 + kc * 32 + quad * 8);
            hu0[kc] = __hip_atomic_load(hp,     __ATOMIC_RELAXED, __HIP_MEMORY_SCOPE_AGENT);
            hu1[kc] = __hip_atomic_load(hp + 1, __ATOMIC_RELAXED, __HIP_MEMORY_SCOPE_AGENT);
        }

        // ---- MFMA: 4 independent 8-deep chains for latency hiding
        floatx4 acc0a = (floatx4){0.f,0.f,0.f,0.f}, acc0b = acc0a;
        floatx4 acc1a = acc0a, acc1b = acc0a;
#pragma unroll
        for (int kc = 0; kc < 8; ++kc) {
            half8 bfrA, bfrB;
            __builtin_memcpy(&bfrA, &hu0[kc], 8);
            __builtin_memcpy((char*)&bfrA + 8, &hu1[kc], 8);
            __builtin_memcpy(&bfrB, &hu0[kc + 8], 8);
            __builtin_memcpy((char*)&bfrB + 8, &hu1[kc + 8], 8);
            acc0a = __builtin_amdgcn_mfma_f32_16x16x32_f16(wf0[kc],     bfrA, acc0a, 0, 0, 0);
            acc0b = __builtin_amdgcn_mfma_f32_16x16x32_f16(wf0[kc + 8], bfrB, acc0b, 0, 0, 0);
            acc1a = __builtin_amdgcn_mfma_f32_16x16x32_f16(wf1[kc],     bfrA, acc1a, 0, 0, 0);
            acc1b = __builtin_amdgcn_mfma_f32_16x16x32_f16(wf1[kc + 8], bfrB, acc1b, 0, 0, 0);
        }

        // add prefetched xg, exchange i/f and g/o halves across lane^32
        float p0[4], p1[4];
#pragma unroll
        for (int r = 0; r < 4; ++r) {
            p0[r] = acc0a[r] + acc0b[r] + xp0[r];
            p1[r] = acc1a[r] + acc1b[r] + xp1[r];
        }
        float e0[4], e1[4];
#pragma unroll
        for (int r = 0; r < 4; ++r) {
            e0[r] = __shfl_xor(p0[r], 32);
            e1[r] = __shfl_xor(p1[r], 32);
        }
#pragma unroll
        for (int r = 0; r < 4; ++r) {
            float iv = (quad < 2) ? p0[r] : e0[r];
            float fv = (quad < 2) ? e0[r] : p0[r];
            float gv = (quad < 2) ? p1[r] : e1[r];
            float ov = (quad < 2) ? e1[r] : p1[r];
            float ii = 1.f / (1.f + __expf(-iv));
            float ff = 1.f / (1.f + __expf(-fv));
            float eg = __expf(-2.f * gv);
            float gg = (1.f - eg) / (1.f + eg);
            float oo = 1.f / (1.f + __expf(-ov));
            float cn = ff * c[r] + ii * gg;
            c[r] = cn;
            float ec = __expf(-2.f * cn);
            hh[r] = oo * ((1.f - ec) / (1.f + ec));
        }

        // h store (sc1 -> LLC) + out store: both BEFORE the single drain so
        // nothing remains outstanding during the spin
        if (quad < 2) {
            _Float16 v4[4] = {(_Float16)hh[0], (_Float16)hh[1],
                              (_Float16)hh[2], (_Float16)hh[3]};
            unsigned long long uv; __builtin_memcpy(&uv, v4, 8);
            __hip_atomic_store((unsigned long long*)(hnxt + (size_t)col * 512 + hbase + (quad & 1) * 4),
                               uv, __ATOMIC_RELAXED, __HIP_MEMORY_SCOPE_AGENT);
            *(float4*)(out + ((size_t)bglob * T + t) * H + hbase + (quad & 1) * 4) =
                make_float4(hh[0], hh[1], hh[2], hh[3]);
        }

        // ---- drain h+out stores, block-level signal: ONE store, own line
        asm volatile("s_waitcnt vmcnt(0)" ::: "memory");
        __syncthreads();
        if (tid == 0)
            __hip_atomic_store(myflg, (unsigned)(t + 2), __ATOMIC_RELAXED, __HIP_MEMORY_SCOPE_AGENT);

        if (t + 1 < T) {
            // xg(t+1): issue AND retire now -- latency overlaps flag
            // propagation; the spin below polls with zero other VMEM pending
            const _Float16* xgt = xg + (size_t)(t + 1) * G * B;
#pragma unroll
            for (int r = 0; r < 4; ++r) {
                xp0[r] = (float)xgt[(size_t)xrow0[r] * B + bglob];
                xp1[r] = (float)xgt[(size_t)xrow1[r] * B + bglob];
            }
            asm volatile("" : "+v"(xp0[0]), "+v"(xp0[1]), "+v"(xp0[2]), "+v"(xp0[3]),
                              "+v"(xp1[0]), "+v"(xp1[1]), "+v"(xp1[2]), "+v"(xp1[3]) :: "memory");

            // spin: 16 distributed flag lines, one coalesced read per poll
            const unsigned tgt = (unsigned)(t + 2);
            for (;;) {
                unsigned f = __hip_atomic_load(flg + (lane & 15) * 16,
                                               __ATOMIC_RELAXED, __HIP_MEMORY_SCOPE_AGENT);
                if (__all(f >= tgt)) break;
            }
            asm volatile("" ::: "memory");
        }
    }

    // final h_T, c_T
    if (quad < 2) {
        float* hT = out + (size_t)B * T * H;
        float* cT = hT + (size_t)B * H;
#pragma unroll
        for (int r = 0; r < 4; ++r) {
            int jj = (quad & 1) * 4 + r;
            hT[(size_t)bglob * H + hbase + jj] = hh[r];
            cT[(size_t)bglob * H + hbase + jj] = c[r];
        }
    }

    // announce completion so burner blocks exit
    asm volatile("s_waitcnt vmcnt(0)" ::: "memory");
    __syncthreads();
    if (tid == 0)
        __hip_atomic_fetch_add(done, 1u, __ATOMIC_RELAXED, __HIP_MEMORY_SCOPE_AGENT);
}

// ---------------------------------------------------------------------------
extern "C" void kernel_launch(void* const* d_in, const int* in_sizes, int n_in,
                              void* d_out, int out_size, void* d_ws, size_t ws_size,
                              hipStream_t stream) {
    const float* x    = (const float*)d_in[0];
    const float* h0   = (const float*)d_in[1];
    const float* c0   = (const float*)d_in[2];
    const float* W_ih = (const float*)d_in[3];
    const float* W_hh = (const float*)d_in[4];
    const float* b_ih = (const float*)d_in[5];
    const float* b_hh = (const float*)d_in[6];
    float* out = (float*)d_out;

    // workspace layout:
    //   [0, 4096)            : 4 groups x 16 block flags, 64B apart, zeroed
    //   [4096, 8192)         : done counter (own line), zeroed
    //   [8192, +128KiB)      : h double buffer (f16)
    //   [next, +T*G*B*2)     : xg (f16), 128 MiB
    unsigned int* flags = (unsigned int*)d_ws;
    unsigned int* done  = (unsigned int*)((char*)d_ws + 4096);
    _Float16* hbuf = (_Float16*)((char*)d_ws + 8192);
    _Float16* xg   = (_Float16*)((char*)d_ws + 8192 + (size_t)2 * 4 * 16 * 512 * 2);

    hipMemsetAsync(d_ws, 0, 8192, stream);

    xg_gemm<<<dim3(16, 128), 256, 0, stream>>>(x, W_ih, b_ih, b_hh, xg);
    lstm_rec<<<256, 256, 0, stream>>>(h0, c0, W_hh, xg, hbuf, flags, done, out);
}